// Round 4
// baseline (58142.139 us; speedup 1.0000x reference)
//
#include <hip/hip_runtime.h>
#include <math.h>

#define RSV   2048
#define NIN   8
#define TT    16384
#define NB    64
#define TB    1024
#define RPB   32          // rows per block
#define RPW   2           // rows per wave
#define OUTW  (RSV+NIN)   // 2056

typedef unsigned long long u64;

// ws layout: buf0 = ws[0..2048) u64, buf1 = ws[2048..4096) u64 (32 KiB)
// word = (stamp << 32) | float_bits

__global__ __launch_bounds__(256) void esn_init(const float* __restrict__ h0,
                                                u64* __restrict__ ws) {
    int i = blockIdx.x * blockDim.x + threadIdx.x;
    if (i < RSV) {
        ws[i]       = (u64)__float_as_uint(h0[i]);  // buf0: stamp 0 | h0 payload
        ws[RSV + i] = 0ull;                         // buf1: stamp 0
    }
}

__device__ __forceinline__ float tanh_fast(float s) {
    return 1.0f - 2.0f / (__expf(2.0f * s) + 1.0f);
}

__global__ __launch_bounds__(TB, 4) void esn_main(const float* __restrict__ x,
                                                  const float* __restrict__ h0,
                                                  const float* __restrict__ Win,
                                                  const float* __restrict__ Wh,
                                                  float* __restrict__ out,
                                                  u64* __restrict__ ws) {
    __shared__ __align__(16) float h_lds[2][RSV];   // double-buffered stage

    const int tid  = threadIdx.x;
    const int b    = blockIdx.x;
    const int wave = tid >> 6;
    const int lane = tid & 63;

    u64* buf0 = ws;
    u64* buf1 = ws + RSV;

    // ---- one-time: Wh into registers (wave: rows row0..row0+1, lane: cols lane+64j) ----
    const int row0 = b * RPB + wave * RPW;
    float wh0[32], wh1[32];
    {
        const float* wr0 = Wh + (size_t)(row0 + 0) * RSV + lane;
        const float* wr1 = Wh + (size_t)(row0 + 1) * RSV + lane;
        #pragma unroll
        for (int j = 0; j < 32; ++j) wh0[j] = wr0[64 * j];
        #pragma unroll
        for (int j = 0; j < 32; ++j) wh1[j] = wr1[64 * j];
    }
    // Pin: asm-opaque values cannot be rematerialized as loads -> stay in VGPRs.
    #pragma unroll
    for (int j = 0; j < 32; ++j) {
        asm volatile("" : "+v"(wh0[j]));
        asm volatile("" : "+v"(wh1[j]));
    }

    const int frow = row0 + (lane & 1);   // producer lanes 0,1 own one row each
    float win[NIN];
    #pragma unroll
    for (int k = 0; k < NIN; ++k) win[k] = Win[frow * NIN + k];
    #pragma unroll
    for (int k = 0; k < NIN; ++k) asm volatile("" : "+v"(win[k]));
    float hp = h0[frow];

    #pragma unroll 1
    for (int t = 1; t <= TT; ++t) {
        const u64* src = (t & 1) ? buf0 : buf1;   // holds h_{t-1}
        u64*       dst = (t & 1) ? buf1 : buf0;   // receives h_t
        float*     hl  = h_lds[t & 1];
        const unsigned want = (unsigned)(t - 1);

        // ---- h-independent work (hides under the poll) ----
        float winx = 0.f;
        if (lane < RPW) {
            const float4* xr = (const float4*)(x + (size_t)(t - 1) * NIN);
            float4 xa = xr[0], xb = xr[1];
            winx = win[0]*xa.x + win[1]*xa.y + win[2]*xa.z + win[3]*xa.w
                 + win[4]*xb.x + win[5]*xb.y + win[6]*xb.z + win[7]*xb.w;
        }
        if (b == 0 && tid < NIN)
            out[(size_t)(t - 1) * OUTW + RSV + tid] = x[(size_t)(t - 1) * NIN + tid];

        // ---- poll OWN 2 stamped words (block collectively covers all 2048) ----
        const u64* sp = src + tid * 2;
        u64 v0, v1;
        for (;;) {
            v0 = __hip_atomic_load(sp + 0, __ATOMIC_RELAXED, __HIP_MEMORY_SCOPE_AGENT);
            v1 = __hip_atomic_load(sp + 1, __ATOMIC_RELAXED, __HIP_MEMORY_SCOPE_AGENT);
            if ((unsigned)(v0 >> 32) >= want && (unsigned)(v1 >> 32) >= want) break;
        }
        float2 hv2;
        hv2.x = __uint_as_float((unsigned)v0);
        hv2.y = __uint_as_float((unsigned)v1);
        *(float2*)&hl[tid * 2] = hv2;
        __syncthreads();   // the ONLY barrier (double-buffered LDS makes WAR safe)

        // ---- 2-row matvec over conflict-free LDS layout ----
        float px = 0.f, py = 0.f;
        #pragma unroll
        for (int j = 0; j < 32; ++j) {
            float hval = hl[lane + 64 * j];
            px += wh0[j] * hval;
            py += wh1[j] * hval;
        }

        // ---- packed butterfly: 6 shuffles total for both rows ----
        float q = (lane & 1) ? py : px;
        float r = (lane & 1) ? px : py;
        q += __shfl_xor(r, 1);                 // even lanes: px-pairs, odd: py-pairs
        #pragma unroll
        for (int m = 2; m <= 32; m <<= 1)
            q += __shfl_xor(q, m);             // lane0: sum(px), lane1: sum(py)

        // ---- producer lanes finalize; stamp store FIRST (unblocks the grid) ----
        if (lane < RPW) {
            float s  = q + winx;
            float ht = 0.9f * hp + 0.1f * tanh_fast(s);
            hp = ht;
            u64 pk = ((u64)(unsigned)t << 32) | (u64)__float_as_uint(ht);
            __hip_atomic_store(dst + frow, pk, __ATOMIC_RELAXED, __HIP_MEMORY_SCOPE_AGENT);
            out[(size_t)(t - 1) * OUTW + frow] = ht;
        }
    }
}

extern "C" void kernel_launch(void* const* d_in, const int* in_sizes, int n_in,
                              void* d_out, int out_size, void* d_ws, size_t ws_size,
                              hipStream_t stream) {
    const float* x   = (const float*)d_in[0];
    const float* h0  = (const float*)d_in[1];
    const float* Win = (const float*)d_in[2];
    const float* Wh  = (const float*)d_in[3];
    float* out = (float*)d_out;
    u64*   ws  = (u64*)d_ws;

    hipLaunchKernelGGL(esn_init, dim3(8), dim3(256), 0, stream, h0, ws);
    hipLaunchKernelGGL(esn_main, dim3(NB), dim3(TB), 0, stream,
                       x, h0, Win, Wh, out, ws);
}

// Round 5
// 40081.360 us; speedup vs baseline: 1.4506x; 1.4506x over previous
//
#include <hip/hip_runtime.h>
#include <math.h>

#define RSV   2048
#define NIN   8
#define TT    16384
#define NB    256
#define TB    1024
#define RPB   8           // rows per block
#define OUTW  (RSV+NIN)   // 2056

typedef unsigned long long u64;

// ws layout: buf0 = ws[0..2048) u64, buf1 = ws[2048..4096) u64 (32 KiB)
// word = (stamp << 32) | float_bits

__global__ __launch_bounds__(256) void esn_init(const float* __restrict__ h0,
                                                u64* __restrict__ ws) {
    int i = blockIdx.x * blockDim.x + threadIdx.x;
    if (i < RSV) {
        ws[i]       = (u64)__float_as_uint(h0[i]);  // buf0: stamp 0 | h0 payload
        ws[RSV + i] = 0ull;                         // buf1: stamp 0
    }
}

__device__ __forceinline__ float tanh_fast(float s) {
    return 1.0f - 2.0f / (__expf(2.0f * s) + 1.0f);
}

__global__ __launch_bounds__(TB, 4) void esn_main(const float* __restrict__ x,
                                                  const float* __restrict__ h0,
                                                  const float* __restrict__ Win,
                                                  const float* __restrict__ Wh,
                                                  float* __restrict__ out,
                                                  u64* __restrict__ ws) {
    __shared__ __align__(16) float h_lds[2][RSV];   // double-buffered h stage (16 KB)
    __shared__ float part_lds[16];                  // per-wave row partials

    const int tid  = threadIdx.x;
    const int b    = blockIdx.x;
    const int wave = tid >> 6;
    const int lane = tid & 63;

    u64* buf0 = ws;
    u64* buf1 = ws + RSV;

    // ---- wave -> (row, column-half): row rw, cols cb + lane + 64j, j=0..15 ----
    const int rw = (b << 3) + (wave >> 1);   // this wave's reservoir row
    const int cb = (wave & 1) << 10;         // column base: 0 or 1024

    // ---- one-time: 16 weights per thread (fits under the allocator's ~52-VGPR target) ----
    float wh[16];
    {
        const float* wr = Wh + (size_t)rw * RSV + cb + lane;
        #pragma unroll
        for (int j = 0; j < 16; ++j) wh[j] = wr[64 * j];
    }

    // producer lanes: wave 0, lanes 0..7 own rows b*8 .. b*8+7
    const int prow = (b << 3) + (lane & 7);
    float win[NIN];
    float hp = 0.f;
    if (wave == 0 && lane < RPB) {
        #pragma unroll
        for (int k = 0; k < NIN; ++k) win[k] = Win[prow * NIN + k];
        hp = h0[prow];
    }

    #pragma unroll 1
    for (int t = 1; t <= TT; ++t) {
        const u64* src = (t & 1) ? buf0 : buf1;   // holds h_{t-1}
        u64*       dst = (t & 1) ? buf1 : buf0;   // receives h_t
        float*     hl  = h_lds[t & 1];
        const unsigned want = (unsigned)(t - 1);

        // ---- h-independent work first (hides L2 latency under the poll) ----
        float winx = 0.f;
        if (wave == 0 && lane < RPB) {
            const float4* xr = (const float4*)(x + (size_t)(t - 1) * NIN);
            float4 xa = xr[0], xb = xr[1];
            winx = win[0]*xa.x + win[1]*xa.y + win[2]*xa.z + win[3]*xa.w
                 + win[4]*xb.x + win[5]*xb.y + win[6]*xb.z + win[7]*xb.w;
        }
        if (b == 0 && wave == 15 && lane < NIN)
            out[(size_t)(t - 1) * OUTW + RSV + lane] = x[(size_t)(t - 1) * NIN + lane];

        // ---- poll OWN 2 stamped words (block collectively covers all 2048) ----
        const u64* sp = src + tid * 2;
        u64 v0, v1;
        for (;;) {
            v0 = __hip_atomic_load(sp + 0, __ATOMIC_RELAXED, __HIP_MEMORY_SCOPE_AGENT);
            v1 = __hip_atomic_load(sp + 1, __ATOMIC_RELAXED, __HIP_MEMORY_SCOPE_AGENT);
            if ((unsigned)(v0 >> 32) >= want && (unsigned)(v1 >> 32) >= want) break;
        }
        float2 hv2;
        hv2.x = __uint_as_float((unsigned)v0);
        hv2.y = __uint_as_float((unsigned)v1);
        *(float2*)&hl[tid * 2] = hv2;
        __syncthreads();   // bar1: h_lds staged (LDS double-buffer => WAR-safe)

        // ---- half-row matvec: 16 FMAs, conflict-free LDS reads (2 lanes/bank) ----
        float acc = 0.f;
        #pragma unroll
        for (int j = 0; j < 16; ++j)
            acc += wh[j] * hl[cb + lane + 64 * j];

        // ---- 64-lane butterfly -> wave partial ----
        #pragma unroll
        for (int m = 32; m >= 1; m >>= 1)
            acc += __shfl_xor(acc, m);
        if (lane == 0) part_lds[wave] = acc;
        __syncthreads();   // bar2: partials visible

        // ---- producers finalize their row; stamp store first ----
        if (wave == 0 && lane < RPB) {
            float s  = part_lds[2 * lane] + part_lds[2 * lane + 1] + winx;
            float ht = 0.9f * hp + 0.1f * tanh_fast(s);
            hp = ht;
            u64 pk = ((u64)(unsigned)t << 32) | (u64)__float_as_uint(ht);
            __hip_atomic_store(dst + prow, pk, __ATOMIC_RELAXED, __HIP_MEMORY_SCOPE_AGENT);
            out[(size_t)(t - 1) * OUTW + prow] = ht;
        }
    }
}

extern "C" void kernel_launch(void* const* d_in, const int* in_sizes, int n_in,
                              void* d_out, int out_size, void* d_ws, size_t ws_size,
                              hipStream_t stream) {
    const float* x   = (const float*)d_in[0];
    const float* h0  = (const float*)d_in[1];
    const float* Win = (const float*)d_in[2];
    const float* Wh  = (const float*)d_in[3];
    float* out = (float*)d_out;
    u64*   ws  = (u64*)d_ws;

    hipLaunchKernelGGL(esn_init, dim3(8), dim3(256), 0, stream, h0, ws);
    hipLaunchKernelGGL(esn_main, dim3(NB), dim3(TB), 0, stream,
                       x, h0, Win, Wh, out, ws);
}

// Round 6
// 30603.134 us; speedup vs baseline: 1.8999x; 1.3097x over previous
//
#include <hip/hip_runtime.h>
#include <math.h>

#define RSV   2048
#define NIN   8
#define TT    16384
#define NB    256
#define TB    512
#define RPB   8           // rows per block = waves per block
#define OUTW  (RSV+NIN)   // 2056

typedef unsigned long long u64;

// ws layout: buf0 = ws[0..2048) u64, buf1 = ws[2048..4096) u64 (32 KiB)
// word = (stamp << 32) | float_bits

__global__ __launch_bounds__(256) void esn_init(const float* __restrict__ h0,
                                                u64* __restrict__ ws) {
    int i = blockIdx.x * blockDim.x + threadIdx.x;
    if (i < RSV) {
        u64 w0 = (u64)__float_as_uint(h0[i]);   // buf0: stamp 0 | h0 payload
        __hip_atomic_store(ws + i,       w0,   __ATOMIC_RELAXED, __HIP_MEMORY_SCOPE_AGENT);
        __hip_atomic_store(ws + RSV + i, 0ull, __ATOMIC_RELAXED, __HIP_MEMORY_SCOPE_AGENT);
    }
}

__device__ __forceinline__ float tanh_fast(float s) {
    return 1.0f - 2.0f / (__expf(2.0f * s) + 1.0f);
}

__global__ __launch_bounds__(TB, 2) void esn_main(const float* __restrict__ x,
                                                  const float* __restrict__ h0,
                                                  const float* __restrict__ Win,
                                                  const float* __restrict__ Wh,
                                                  float* __restrict__ out,
                                                  u64* __restrict__ ws) {
    __shared__ __align__(16) float h_lds[2][RSV];   // double-buffered h stage (16 KB)

    const int tid  = threadIdx.x;
    const int b    = blockIdx.x;
    const int wave = tid >> 6;
    const int lane = tid & 63;

    u64* buf0 = ws;
    u64* buf1 = ws + RSV;

    // ---- wave owns one full row; lane owns cols {lane + 64j}, j=0..31 ----
    const int row = (b << 3) + wave;
    float wh[32];
    {
        const float* wr = Wh + (size_t)row * RSV + lane;
        #pragma unroll
        for (int j = 0; j < 32; ++j) wh[j] = wr[64 * j];
    }
    float hp = (lane == 0) ? h0[row] : 0.f;

    #pragma unroll 1
    for (int t = 1; t <= TT; ++t) {
        const u64* src = (t & 1) ? buf0 : buf1;   // holds h_{t-1} (stamps t-1)
        u64*       dst = (t & 1) ? buf1 : buf0;   // receives h_t (stamps t)
        float*     hl  = h_lds[t & 1];
        const unsigned want = (unsigned)(t - 1);

        // ---- h-independent work first (hidden under the poll) ----
        float winx = 0.f;
        if (lane == 0) {
            const float4* wr4 = (const float4*)(Win + row * NIN);   // L1-hot 32 B
            const float4* xr4 = (const float4*)(x + (size_t)(t - 1) * NIN);
            float4 wa = wr4[0], wb = wr4[1];
            float4 xa = xr4[0], xb = xr4[1];
            winx = wa.x*xa.x + wa.y*xa.y + wa.z*xa.z + wa.w*xa.w
                 + wb.x*xb.x + wb.y*xb.y + wb.z*xb.z + wb.w*xb.w;
        }
        if (b == 0 && wave == 0 && lane >= 8 && lane < 8 + NIN)
            out[(size_t)(t - 1) * OUTW + RSV + (lane - 8)] = x[(size_t)(t - 1) * NIN + (lane - 8)];

        // ---- poll OWN 4 stamped words (block collectively covers all 2048).
        //      Payload rides the same 8B word: consumption is complete at poll-pass. ----
        const u64* sp = src + tid * 4;
        u64 v0, v1, v2, v3;
        for (;;) {
            v0 = __hip_atomic_load(sp + 0, __ATOMIC_RELAXED, __HIP_MEMORY_SCOPE_AGENT);
            v1 = __hip_atomic_load(sp + 1, __ATOMIC_RELAXED, __HIP_MEMORY_SCOPE_AGENT);
            v2 = __hip_atomic_load(sp + 2, __ATOMIC_RELAXED, __HIP_MEMORY_SCOPE_AGENT);
            v3 = __hip_atomic_load(sp + 3, __ATOMIC_RELAXED, __HIP_MEMORY_SCOPE_AGENT);
            if ((unsigned)(v0 >> 32) >= want && (unsigned)(v1 >> 32) >= want &&
                (unsigned)(v2 >> 32) >= want && (unsigned)(v3 >> 32) >= want) break;
        }
        float4 hv4;
        hv4.x = __uint_as_float((unsigned)v0);
        hv4.y = __uint_as_float((unsigned)v1);
        hv4.z = __uint_as_float((unsigned)v2);
        hv4.w = __uint_as_float((unsigned)v3);
        *(float4*)&hl[tid * 4] = hv4;
        __syncthreads();   // the ONLY barrier per step

        // ---- full-row matvec: 32 FMAs, conflict-free LDS reads (2 lanes/bank) ----
        float acc = 0.f;
        #pragma unroll
        for (int j = 0; j < 32; ++j)
            acc += wh[j] * hl[lane + 64 * j];

        // ---- 64-lane butterfly -> row sum in lane 0 ----
        #pragma unroll
        for (int m = 32; m >= 1; m >>= 1)
            acc += __shfl_xor(acc, m);

        // ---- lane 0 finalizes its row; stamp store first (unblocks the grid) ----
        if (lane == 0) {
            float s  = acc + winx;
            float ht = 0.9f * hp + 0.1f * tanh_fast(s);
            hp = ht;
            u64 pk = ((u64)(unsigned)t << 32) | (u64)__float_as_uint(ht);
            __hip_atomic_store(dst + row, pk, __ATOMIC_RELAXED, __HIP_MEMORY_SCOPE_AGENT);
            out[(size_t)(t - 1) * OUTW + row] = ht;
        }
    }
}

extern "C" void kernel_launch(void* const* d_in, const int* in_sizes, int n_in,
                              void* d_out, int out_size, void* d_ws, size_t ws_size,
                              hipStream_t stream) {
    const float* x   = (const float*)d_in[0];
    const float* h0  = (const float*)d_in[1];
    const float* Win = (const float*)d_in[2];
    const float* Wh  = (const float*)d_in[3];
    float* out = (float*)d_out;
    u64*   ws  = (u64*)d_ws;

    hipLaunchKernelGGL(esn_init, dim3(8), dim3(256), 0, stream, h0, ws);
    hipLaunchKernelGGL(esn_main, dim3(NB), dim3(TB), 0, stream,
                       x, h0, Win, Wh, out, ws);
}